// Round 7
// baseline (393.338 us; speedup 1.0000x reference)
//
#include <hip/hip_runtime.h>
#include <stdint.h>
#include <math.h>

#define THREADS 256
#define NBINS 65536
#define CANDCAP 8128
#define NEGV (-1e30f)
#define NLEV 15        // qw,qh in [-5, 9] -> t = q+5 in [0,14]
#define ODDMULT 0x9E3779B1u

struct GridCfg {
    int prefX[NLEV], prefY[NLEV], nx[NLEV], ny[NLEV];
    int totY;
};

__device__ __forceinline__ uint32_t f2ord(float f) {
    uint32_t u = __float_as_uint(f);
    return (u & 0x80000000u) ? ~u : (u | 0x80000000u);
}
__device__ __forceinline__ float ord2f(uint32_t u) {
    uint32_t b = (u & 0x80000000u) ? (u ^ 0x80000000u) : ~u;
    return __uint_as_float(b);
}

// Perfect-hash slot for one (box, offset): odd-mult scatter over [0, 2^22).
// Injective while TOT <= 2^22 (odd mult is bijective mod 2^22); spreads hot
// coarse-level cells across all L2/IF$ channels so atomic RMWs parallelize.
// Numerics must bit-match the reference: f32 ops, no FMA contraction,
// correctly-rounded log/pow via double.
__device__ __forceinline__ uint32_t slot_of(float cx, float cy, float Lw, float Lh,
                                            float dw, float dh, float dx, float dy,
                                            const float* __restrict__ powtab,
                                            const GridCfg& g, uint32_t mult,
                                            uint32_t smask) {
#pragma clang fp contract(off)
    float qw = floorf(Lw + dw);
    float qh = floorf(Lh + dh);
    int iw = (int)qw, ih = (int)qh;
    int t = iw + 5; t = t < 0 ? 0 : (t > NLEV - 1 ? NLEV - 1 : t);
    int u = ih + 5; u = u < 0 ? 0 : (u > NLEV - 1 ? NLEV - 1 : u);
    float cellx = 9.6f * powtab[t];
    float celly = 9.6f * powtab[u];
    float qx = floorf(cx / cellx + dx);
    float qy = floorf(cy / celly + dy);
    int ix = (int)qx, iy = (int)qy;
    ix = ix < 0 ? 0 : (ix > g.nx[t] - 1 ? g.nx[t] - 1 : ix);
    iy = iy < 0 ? 0 : (iy > g.ny[u] - 1 ? g.ny[u] - 1 : iy);
    uint32_t cell = (uint32_t)((g.prefX[t] + ix) * g.totY + (g.prefY[u] + iy));
    return (cell * mult) & smask;
}

__device__ __forceinline__ void load_tabs(const float* __restrict__ offs, int num_off,
                                          float* powtab, float* soff) {
    int t = threadIdx.x;
    if (t < NLEV) powtab[t] = (float)pow((double)1.4f, (double)(t - 5));
    if (t >= 32 && t - 32 < num_off * 4) soff[t - 32] = offs[t - 32];
    __syncthreads();
}

// ---- insert: fire-and-forget 64-bit atomicMax per (box, offset). ----
// No filter read: atomicMax with unused result is a non-returning
// global_atomic_umax — no vmcnt dependency, waves never stall on it.
// Scattered layout keeps per-LINE conflict depth == per-CELL depth.
// Stage 1: xor_mask=0x80000000 (ord MSB cleared, since s in [0,1)).
// Stage 2: xor_mask=0, svals<0 (killed) skip; MSB=1 beats stale stage-1 data.
__global__ void k_insert(const float4* __restrict__ rects,
                         const float* __restrict__ svals,
                         const float* __restrict__ offs, int num_off,
                         uint64_t* __restrict__ vals,
                         int N, GridCfg g, uint32_t slots, uint32_t mult,
                         uint32_t smask, uint32_t xor_mask) {
#pragma clang fp contract(off)
    __shared__ float powtab[NLEV];
    __shared__ float soff[16];
    load_tabs(offs, num_off, powtab, soff);
    int i = blockIdx.x * blockDim.x + threadIdx.x;
    if (i >= N) return;

    float s = svals[i];
    if (s < 0.0f) return;
    float4 r = rects[i];
    uint64_t packed = ((uint64_t)(f2ord(s) ^ xor_mask) << 32) | (uint32_t)(~(uint32_t)i);

    const float lg = (float)log((double)1.4f);
    float Lw = (float)log((double)(r.z * 0.0625f)) / lg;
    float Lh = (float)log((double)(r.w * 0.0625f)) / lg;

    for (int k = 0; k < num_off; ++k) {
        uint32_t sl = slot_of(r.x, r.y, Lw, Lh,
                              soff[k * 4 + 0], soff[k * 4 + 1],
                              soff[k * 4 + 2], soff[k * 4 + 3], powtab, g,
                              mult, smask);
        atomicMax((unsigned long long*)&vals[(uint64_t)k * slots + sl],
                  (unsigned long long)packed);
    }
}

// ---- stage1 resolve: keep iff winner of every bucket; mscore = keep?s:NEG ----
__global__ void k_resolve1(const float4* __restrict__ rects,
                           const float* __restrict__ scores,
                           const float* __restrict__ offs, int num_off,
                           const uint64_t* __restrict__ vals,
                           float* __restrict__ mscore,
                           int N, GridCfg g, uint32_t slots, uint32_t mult,
                           uint32_t smask) {
#pragma clang fp contract(off)
    __shared__ float powtab[NLEV];
    __shared__ float soff[16];
    load_tabs(offs, num_off, powtab, soff);
    int i = blockIdx.x * blockDim.x + threadIdx.x;
    if (i >= N) return;

    float4 r = rects[i];
    const float lg = (float)log((double)1.4f);
    float Lw = (float)log((double)(r.z * 0.0625f)) / lg;
    float Lh = (float)log((double)(r.w * 0.0625f)) / lg;

    bool keep = true;
    for (int k = 0; k < num_off; ++k) {
        uint32_t sl = slot_of(r.x, r.y, Lw, Lh,
                              soff[k * 4 + 0], soff[k * 4 + 1],
                              soff[k * 4 + 2], soff[k * 4 + 3], powtab, g,
                              mult, smask);
        uint64_t v = vals[(uint64_t)k * slots + sl];
        keep = keep && ((~(uint32_t)v) == (uint32_t)i);
    }
    mscore[i] = keep ? scores[i] : NEGV;
}

// ---- stage2 resolve: IoU vs bucket representative; combine; histogram. ----
__global__ void k_resolve2(const float4* __restrict__ rects,
                           const float* __restrict__ scores,
                           const float* __restrict__ mscore,
                           const float* __restrict__ offs, int num_off,
                           const uint64_t* __restrict__ vals,
                           float* __restrict__ finals,
                           uint32_t* __restrict__ hist,
                           int N, GridCfg g, uint32_t slots, uint32_t mult,
                           uint32_t smask) {
#pragma clang fp contract(off)
    __shared__ float powtab[NLEV];
    __shared__ float soff[16];
    load_tabs(offs, num_off, powtab, soff);
    int i = blockIdx.x * blockDim.x + threadIdx.x;
    if (i >= N) return;

    if (mscore[i] < 0.0f) { finals[i] = NEGV; return; }

    float4 a = rects[i];
    const float lg = (float)log((double)1.4f);
    float Lw = (float)log((double)(a.z * 0.0625f)) / lg;
    float Lh = (float)log((double)(a.w * 0.0625f)) / lg;
    bool keep = true;
    for (int k = 0; k < num_off && keep; ++k) {
        uint32_t sl = slot_of(a.x, a.y, Lw, Lh,
                              soff[k * 4 + 0], soff[k * 4 + 1],
                              soff[k * 4 + 2], soff[k * 4 + 3], powtab, g,
                              mult, smask);
        uint64_t v = vals[(uint64_t)k * slots + sl];
        uint32_t rep = ~(uint32_t)v;
        if (rep != (uint32_t)i) {
            float4 b = rects[rep];
            float ax1 = a.x - 0.5f * a.z, ay1 = a.y - 0.5f * a.w;
            float ax2 = a.x + 0.5f * a.z, ay2 = a.y + 0.5f * a.w;
            float bx1 = b.x - 0.5f * b.z, by1 = b.y - 0.5f * b.w;
            float bx2 = b.x + 0.5f * b.z, by2 = b.y + 0.5f * b.w;
            float iw = fminf(ax2, bx2) - fmaxf(ax1, bx1); iw = fmaxf(iw, 0.0f);
            float ih = fminf(ay2, by2) - fmaxf(ay1, by1); ih = fmaxf(ih, 0.0f);
            float inter = iw * ih;
            float uni = a.z * a.w + b.z * b.w - inter;
            float iou = inter / fmaxf(uni, 1e-12f);
            keep = keep && (iou <= 0.5f);
        }
    }
    float s = scores[i];
    finals[i] = keep ? s : NEGV;
    if (keep) {
        int b = (int)(s * 65536.0f);
        b = b < 0 ? 0 : (b > NBINS - 1 ? NBINS - 1 : b);
        atomicAdd(&hist[b], 1u);
    }
}

// ---- threshold bin: largest T with count(bin >= T) >= K ----
__global__ void k_thresh(const uint32_t* __restrict__ hist, int* scalars, int K) {
    __shared__ uint32_t sh[1024];
    __shared__ int tmax;
    __shared__ uint32_t running_s;
    int t = threadIdx.x;
    if (t == 0) { running_s = 0; scalars[0] = 0; }
    __syncthreads();
    for (int base = NBINS - 1024; base >= 0; base -= 1024) {
        if (t == 0) tmax = -1;
        sh[t] = hist[base + t];
        __syncthreads();
        for (int off = 1; off < 1024; off <<= 1) {
            uint32_t v = (t + off < 1024) ? sh[t + off] : 0u;
            __syncthreads();
            sh[t] += v;
            __syncthreads();
        }
        if (running_s + sh[t] >= (uint32_t)K) atomicMax(&tmax, t);
        __syncthreads();
        if (tmax >= 0) {
            if (t == 0) scalars[0] = base + tmax;
            return;
        }
        if (t == 0) running_s += sh[0];
        __syncthreads();
    }
}

// ---- compact candidates above threshold bin ----
__global__ void k_compact(const float* __restrict__ finals,
                          uint64_t* __restrict__ cand, int* scalars, int N) {
    int i = blockIdx.x * blockDim.x + threadIdx.x;
    if (i >= N) return;
    float v = finals[i];
    if (v >= 0.0f) {
        int b = (int)(v * 65536.0f);
        b = b < 0 ? 0 : (b > NBINS - 1 ? NBINS - 1 : b);
        if (b >= scalars[0]) {
            int pos = atomicAdd(&scalars[1], 1);
            if (pos < CANDCAP)
                cand[pos] = ((uint64_t)f2ord(v) << 32) | (uint32_t)(~(uint32_t)i);
        }
    }
}

// ---- exact rank (value desc, idx asc), emit [rects[idx], val] rows ----
__global__ void k_topk(const float4* __restrict__ rects,
                       const uint64_t* __restrict__ cand,
                       const int* __restrict__ scalars,
                       float* __restrict__ out, int K) {
    __shared__ uint64_t sc[CANDCAP];
    int t = threadIdx.x;
    int M = scalars[1]; if (M > CANDCAP) M = CANDCAP;
    for (int j = t; j < M; j += blockDim.x) sc[j] = cand[j];
    __syncthreads();
    for (int j = t; j < M; j += blockDim.x) {
        uint64_t me = sc[j];
        int rank = 0;
        for (int k = 0; k < M; ++k) rank += (sc[k] > me) ? 1 : 0;
        if (rank < K) {
            uint32_t idx = ~(uint32_t)me;
            float v = ord2f((uint32_t)(me >> 32));
            float4 r = rects[idx];
            float* o = out + (size_t)rank * 5;
            o[0] = r.x; o[1] = r.y; o[2] = r.z; o[3] = r.w; o[4] = v;
        }
    }
}

extern "C" void kernel_launch(void* const* d_in, const int* in_sizes, int n_in,
                              void* d_out, int out_size, void* d_ws, size_t ws_size,
                              hipStream_t stream) {
    const float4* rects = (const float4*)d_in[0];
    const float* scores = (const float*)d_in[1];
    const float* off1 = (const float*)d_in[2];
    const float* off2 = (const float*)d_in[3];
    int N = in_sizes[0] / 4;
    int num1 = in_sizes[2] / 4;
    int num2 = in_sizes[3] / 4;
    int NT = num1 > num2 ? num1 : num2;
    int K = out_size / 5;
    float* out = (float*)d_out;

    GridCfg g;
    int px = 0, py = 0;
    for (int q = 0; q < NLEV; ++q) {
        double cell = 9.6 * pow(1.4, (double)(q - 5));
        int nx = (int)floor(1333.0 / cell) + 2;
        int ny = (int)floor(800.0 / cell) + 2;
        g.nx[q] = nx; g.ny[q] = ny;
        g.prefX[q] = px; g.prefY[q] = py;
        px += nx; py += ny;
    }
    g.totY = py;
    uint64_t TOT = (uint64_t)px * (uint64_t)py;   // ~4.15M cells

    uint32_t slots, mult, smask;
    if (TOT <= (1u << 22)) {
        slots = 1u << 22; mult = ODDMULT; smask = slots - 1;
    } else {
        slots = (uint32_t)TOT; mult = 1u; smask = 0xFFFFFFFFu;
    }

    char* p = (char*)d_ws;
    uint64_t* vals = (uint64_t*)p; p += (size_t)NT * slots * 8;
    uint32_t* hist = (uint32_t*)p; p += (size_t)NBINS * 4;
    int* scalars   = (int*)p;      p += 256;
    uint64_t* cand = (uint64_t*)p; p += (size_t)CANDCAP * 8;
    float* mscore  = (float*)p;    p += (size_t)N * 4;
    float* finals  = (float*)p;

    size_t tblBytes = (size_t)NT * slots * 8;
    int blocks = (N + THREADS - 1) / THREADS;

    // one zero-init covers tables + hist + scalars (contiguous)
    hipMemsetAsync(vals, 0, tblBytes + (size_t)NBINS * 4 + 256, stream);

    // stage 1 (ord MSB cleared -> all stage-1 entries lose to stage-2 ones)
    k_insert<<<blocks, THREADS, 0, stream>>>(rects, scores, off1, num1, vals,
                                             N, g, slots, mult, smask, 0x80000000u);
    k_resolve1<<<blocks, THREADS, 0, stream>>>(rects, scores, off1, num1, vals,
                                               mscore, N, g, slots, mult, smask);

    // stage 2: tables reused WITHOUT clearing (epoch trick); killed boxes skip
    k_insert<<<blocks, THREADS, 0, stream>>>(rects, mscore, off2, num2, vals,
                                             N, g, slots, mult, smask, 0u);
    k_resolve2<<<blocks, THREADS, 0, stream>>>(rects, scores, mscore, off2, num2,
                                               vals, finals, hist, N, g, slots,
                                               mult, smask);

    // top-k
    k_thresh<<<1, 1024, 0, stream>>>(hist, scalars, K);
    k_compact<<<blocks, THREADS, 0, stream>>>(finals, cand, scalars, N);
    k_topk<<<1, 1024, 0, stream>>>(rects, cand, scalars, out, K);
}

// Round 8
// 279.107 us; speedup vs baseline: 1.4093x; 1.4093x over previous
//
#include <hip/hip_runtime.h>
#include <stdint.h>
#include <math.h>

#define THREADS 256
#define NBINS 65536
#define CANDCAP 8128
#define NLEV 15        // qw,qh in [-5, 9] -> t = q+5 in [0,14]
#define ODDMULT 0x9E3779B1u
#define SGRID 2048     // grid-stride blocks for list-driven passes

struct GridCfg {
    int prefX[NLEV], prefY[NLEV], nx[NLEV], ny[NLEV];
    int totY;
};

__device__ __forceinline__ uint32_t f2ord(float f) {
    uint32_t u = __float_as_uint(f);
    return (u & 0x80000000u) ? ~u : (u | 0x80000000u);
}
__device__ __forceinline__ float ord2f(uint32_t u) {
    uint32_t b = (u & 0x80000000u) ? (u ^ 0x80000000u) : ~u;
    return __uint_as_float(b);
}

// Perfect-hash slot: odd-mult scatter over [0, 2^22) (bijective while
// TOT <= 2^22). Numerics must bit-match the reference: f32 ops, no FMA
// contraction, correctly-rounded log/pow via double.
__device__ __forceinline__ uint32_t slot_of(float cx, float cy, float Lw, float Lh,
                                            float dw, float dh, float dx, float dy,
                                            const float* __restrict__ powtab,
                                            const GridCfg& g, uint32_t mult,
                                            uint32_t smask) {
#pragma clang fp contract(off)
    float qw = floorf(Lw + dw);
    float qh = floorf(Lh + dh);
    int iw = (int)qw, ih = (int)qh;
    int t = iw + 5; t = t < 0 ? 0 : (t > NLEV - 1 ? NLEV - 1 : t);
    int u = ih + 5; u = u < 0 ? 0 : (u > NLEV - 1 ? NLEV - 1 : u);
    float cellx = 9.6f * powtab[t];
    float celly = 9.6f * powtab[u];
    float qx = floorf(cx / cellx + dx);
    float qy = floorf(cy / celly + dy);
    int ix = (int)qx, iy = (int)qy;
    ix = ix < 0 ? 0 : (ix > g.nx[t] - 1 ? g.nx[t] - 1 : ix);
    iy = iy < 0 ? 0 : (iy > g.ny[u] - 1 ? g.ny[u] - 1 : iy);
    uint32_t cell = (uint32_t)((g.prefX[t] + ix) * g.totY + (g.prefY[u] + iy));
    return (cell * mult) & smask;
}

__device__ __forceinline__ void load_tabs(const float* __restrict__ offs, int num_off,
                                          float* powtab, float* soff) {
    int t = threadIdx.x;
    if (t < NLEV) powtab[t] = (float)pow((double)1.4f, (double)(t - 5));
    if (t >= 32 && t - 32 < num_off * 4) soff[t - 32] = offs[t - 32];
    __syncthreads();
}

__device__ __forceinline__ void compute_LwLh(float w, float h, float& Lw, float& Lh) {
#pragma clang fp contract(off)
    const float lg = (float)log((double)1.4f);
    Lw = (float)log((double)(w * 0.0625f)) / lg;
    Lh = (float)log((double)(h * 0.0625f)) / lg;
}

// ---- insert1: filtered RETURNING atomicMax; boxes that lead all buckets at
// commit time append packed1 to provisional list P (block-aggregated).
// Guarantees: true winner always passes (filter reads and old values are
// committed monotone values < its packed); losers may sneak in (verified
// later). packed1 has MSB=0 (ord ^ 0x80000000, valid since s in [0,1)) so
// stage-2 values (MSB=1) beat all stage-1 residue (epoch trick).
__global__ void k_insert1(const float4* __restrict__ rects,
                          const float* __restrict__ scores,
                          const float* __restrict__ offs, int num_off,
                          uint64_t* __restrict__ vals,
                          uint64_t* __restrict__ P,
                          uint32_t* __restrict__ scal,
                          int N, GridCfg g, uint32_t slots, uint32_t mult,
                          uint32_t smask) {
#pragma clang fp contract(off)
    __shared__ float powtab[NLEV];
    __shared__ float soff[32];
    __shared__ uint32_t l_cnt, l_base;
    if (threadIdx.x == 0) l_cnt = 0;
    load_tabs(offs, num_off, powtab, soff);   // contains __syncthreads()

    int i = blockIdx.x * blockDim.x + threadIdx.x;
    bool win = false;
    uint64_t packed = 0;
    if (i < N) {
        float4 r = rects[i];
        float s = scores[i];
        packed = ((uint64_t)(f2ord(s) ^ 0x80000000u) << 32) | (uint32_t)(~(uint32_t)i);
        float Lw, Lh; compute_LwLh(r.z, r.w, Lw, Lh);
        uint32_t sl[8];
        for (int k = 0; k < num_off; ++k)
            sl[k] = slot_of(r.x, r.y, Lw, Lh,
                            soff[k * 4 + 0], soff[k * 4 + 1],
                            soff[k * 4 + 2], soff[k * 4 + 3], powtab, g, mult, smask);
        uint64_t cur[8];
        for (int k = 0; k < num_off; ++k)
            cur[k] = vals[(uint64_t)k * slots + sl[k]];
        win = true;
        for (int k = 0; k < num_off; ++k) {
            if (cur[k] < packed) {
                unsigned long long old =
                    atomicMax((unsigned long long*)&vals[(uint64_t)k * slots + sl[k]],
                              (unsigned long long)packed);
                win = win && ((uint64_t)old < packed);
            } else {
                win = false;
            }
        }
    }
    uint32_t pos = 0;
    if (win) pos = atomicAdd(&l_cnt, 1u);
    __syncthreads();
    if (threadIdx.x == 0 && l_cnt) l_base = atomicAdd(&scal[2], l_cnt);
    __syncthreads();
    if (win) P[l_base + pos] = packed;
}

// ---- confirm (resolve1 over P only): keep iff still winner of every bucket;
// survivors S hold stage-2 packed (MSB flipped back on). Table is read-only
// during this kernel, so cached copies are final post-insert1 values.
__global__ void k_confirm(const float4* __restrict__ rects,
                          const float* __restrict__ offs, int num_off,
                          const uint64_t* __restrict__ vals,
                          const uint64_t* __restrict__ P,
                          uint64_t* __restrict__ S,
                          uint32_t* __restrict__ scal,
                          GridCfg g, uint32_t slots, uint32_t mult,
                          uint32_t smask) {
#pragma clang fp contract(off)
    __shared__ float powtab[NLEV];
    __shared__ float soff[32];
    __shared__ uint32_t l_cnt, l_base;
    load_tabs(offs, num_off, powtab, soff);
    uint32_t total = scal[2];
    uint32_t stride = gridDim.x * blockDim.x;
    for (uint32_t base = blockIdx.x * blockDim.x; base < total; base += stride) {
        if (threadIdx.x == 0) l_cnt = 0;
        __syncthreads();
        uint32_t j = base + threadIdx.x;
        bool ok = false;
        uint64_t p1 = 0;
        if (j < total) {
            p1 = P[j];
            uint32_t i = ~(uint32_t)p1;
            float4 r = rects[i];
            float Lw, Lh; compute_LwLh(r.z, r.w, Lw, Lh);
            ok = true;
            for (int k = 0; k < num_off; ++k) {
                uint32_t sl = slot_of(r.x, r.y, Lw, Lh,
                                      soff[k * 4 + 0], soff[k * 4 + 1],
                                      soff[k * 4 + 2], soff[k * 4 + 3],
                                      powtab, g, mult, smask);
                ok = ok && (vals[(uint64_t)k * slots + sl] == p1);
            }
        }
        uint32_t pos = 0;
        if (ok) pos = atomicAdd(&l_cnt, 1u);
        __syncthreads();
        if (threadIdx.x == 0 && l_cnt) l_base = atomicAdd(&scal[3], l_cnt);
        __syncthreads();
        if (ok) S[l_base + pos] = p1 ^ 0x8000000000000000ull;   // stage-2 packed
        __syncthreads();
    }
}

// ---- insert2: filtered non-returning atomicMax for survivors only.
// Stage-2 packed has MSB=1 -> beats any stale stage-1 entry (epoch trick).
__global__ void k_insert2(const float4* __restrict__ rects,
                          const float* __restrict__ offs, int num_off,
                          uint64_t* __restrict__ vals,
                          const uint64_t* __restrict__ S,
                          const uint32_t* __restrict__ scal,
                          GridCfg g, uint32_t slots, uint32_t mult,
                          uint32_t smask) {
#pragma clang fp contract(off)
    __shared__ float powtab[NLEV];
    __shared__ float soff[32];
    load_tabs(offs, num_off, powtab, soff);
    uint32_t total = scal[3];
    uint32_t stride = gridDim.x * blockDim.x;
    for (uint32_t j = blockIdx.x * blockDim.x + threadIdx.x; j < total; j += stride) {
        uint64_t p2 = S[j];
        uint32_t i = ~(uint32_t)p2;
        float4 r = rects[i];
        float Lw, Lh; compute_LwLh(r.z, r.w, Lw, Lh);
        uint32_t sl[8];
        for (int k = 0; k < num_off; ++k)
            sl[k] = slot_of(r.x, r.y, Lw, Lh,
                            soff[k * 4 + 0], soff[k * 4 + 1],
                            soff[k * 4 + 2], soff[k * 4 + 3], powtab, g, mult, smask);
        uint64_t cur[8];
        for (int k = 0; k < num_off; ++k)
            cur[k] = vals[(uint64_t)k * slots + sl[k]];
        for (int k = 0; k < num_off; ++k)
            if (cur[k] < p2)
                atomicMax((unsigned long long*)&vals[(uint64_t)k * slots + sl[k]],
                          (unsigned long long)p2);
    }
}

// ---- resolve2: survivors only. rep = final stage-2 bucket winner (my bucket
// always holds an MSB=1 value >= mine). keep iff rep==me or IoU<=0.5 in all
// tables; keepers -> histogram + keeplist (block-aggregated).
__global__ void k_resolve2(const float4* __restrict__ rects,
                           const float* __restrict__ offs, int num_off,
                           const uint64_t* __restrict__ vals,
                           const uint64_t* __restrict__ S,
                           uint64_t* __restrict__ KL,
                           uint32_t* __restrict__ hist,
                           uint32_t* __restrict__ scal,
                           GridCfg g, uint32_t slots, uint32_t mult,
                           uint32_t smask) {
#pragma clang fp contract(off)
    __shared__ float powtab[NLEV];
    __shared__ float soff[32];
    __shared__ uint32_t l_cnt, l_base;
    load_tabs(offs, num_off, powtab, soff);
    uint32_t total = scal[3];
    uint32_t stride = gridDim.x * blockDim.x;
    for (uint32_t base = blockIdx.x * blockDim.x; base < total; base += stride) {
        if (threadIdx.x == 0) l_cnt = 0;
        __syncthreads();
        uint32_t j = base + threadIdx.x;
        bool keep = false;
        uint64_t p2 = 0;
        float s = 0.0f;
        if (j < total) {
            p2 = S[j];
            uint32_t i = ~(uint32_t)p2;
            s = ord2f((uint32_t)(p2 >> 32));
            float4 a = rects[i];
            float Lw, Lh; compute_LwLh(a.z, a.w, Lw, Lh);
            keep = true;
            for (int k = 0; k < num_off && keep; ++k) {
                uint32_t sl = slot_of(a.x, a.y, Lw, Lh,
                                      soff[k * 4 + 0], soff[k * 4 + 1],
                                      soff[k * 4 + 2], soff[k * 4 + 3],
                                      powtab, g, mult, smask);
                uint64_t v = vals[(uint64_t)k * slots + sl];
                uint32_t rep = ~(uint32_t)v;
                if (rep != i) {
                    float4 b = rects[rep];
                    float ax1 = a.x - 0.5f * a.z, ay1 = a.y - 0.5f * a.w;
                    float ax2 = a.x + 0.5f * a.z, ay2 = a.y + 0.5f * a.w;
                    float bx1 = b.x - 0.5f * b.z, by1 = b.y - 0.5f * b.w;
                    float bx2 = b.x + 0.5f * b.z, by2 = b.y + 0.5f * b.w;
                    float iw = fminf(ax2, bx2) - fmaxf(ax1, bx1); iw = fmaxf(iw, 0.0f);
                    float ih = fminf(ay2, by2) - fmaxf(ay1, by1); ih = fmaxf(ih, 0.0f);
                    float inter = iw * ih;
                    float uni = a.z * a.w + b.z * b.w - inter;
                    float iou = inter / fmaxf(uni, 1e-12f);
                    keep = keep && (iou <= 0.5f);
                }
            }
        }
        if (keep) {
            int b = (int)(s * 65536.0f);
            b = b < 0 ? 0 : (b > NBINS - 1 ? NBINS - 1 : b);
            atomicAdd(&hist[b], 1u);
        }
        uint32_t pos = 0;
        if (keep) pos = atomicAdd(&l_cnt, 1u);
        __syncthreads();
        if (threadIdx.x == 0 && l_cnt) l_base = atomicAdd(&scal[4], l_cnt);
        __syncthreads();
        if (keep) KL[l_base + pos] = p2;
        __syncthreads();
    }
}

// ---- threshold bin: largest T with count(bin >= T) >= K ----
__global__ void k_thresh(const uint32_t* __restrict__ hist,
                         uint32_t* __restrict__ scal, int K) {
    __shared__ uint32_t sh[1024];
    __shared__ int tmax;
    __shared__ uint32_t running_s;
    int t = threadIdx.x;
    if (t == 0) { running_s = 0; scal[0] = 0; }
    __syncthreads();
    for (int base = NBINS - 1024; base >= 0; base -= 1024) {
        if (t == 0) tmax = -1;
        sh[t] = hist[base + t];
        __syncthreads();
        for (int off = 1; off < 1024; off <<= 1) {
            uint32_t v = (t + off < 1024) ? sh[t + off] : 0u;
            __syncthreads();
            sh[t] += v;
            __syncthreads();
        }
        if (running_s + sh[t] >= (uint32_t)K) atomicMax(&tmax, t);
        __syncthreads();
        if (tmax >= 0) {
            if (t == 0) scal[0] = (uint32_t)(base + tmax);
            return;
        }
        if (t == 0) running_s += sh[0];
        __syncthreads();
    }
}

// ---- compact keepers above threshold bin into cand ----
__global__ void k_compact(const uint64_t* __restrict__ KL,
                          uint64_t* __restrict__ cand,
                          uint32_t* __restrict__ scal) {
    uint32_t total = scal[4];
    uint32_t thr = scal[0];
    uint32_t stride = gridDim.x * blockDim.x;
    for (uint32_t j = blockIdx.x * blockDim.x + threadIdx.x; j < total; j += stride) {
        uint64_t p = KL[j];
        float v = ord2f((uint32_t)(p >> 32));
        int b = (int)(v * 65536.0f);
        b = b < 0 ? 0 : (b > NBINS - 1 ? NBINS - 1 : b);
        if (b >= (int)thr) {
            uint32_t pos = atomicAdd(&scal[1], 1u);
            if (pos < CANDCAP) cand[pos] = p;
        }
    }
}

// ---- exact rank (value desc, idx asc), emit [rects[idx], val] rows ----
__global__ void k_topk(const float4* __restrict__ rects,
                       const uint64_t* __restrict__ cand,
                       const uint32_t* __restrict__ scal,
                       float* __restrict__ out, int K) {
    __shared__ uint64_t sc[CANDCAP];
    int t = threadIdx.x;
    int M = (int)scal[1]; if (M > CANDCAP) M = CANDCAP;
    for (int j = t; j < M; j += blockDim.x) sc[j] = cand[j];
    __syncthreads();
    for (int j = t; j < M; j += blockDim.x) {
        uint64_t me = sc[j];
        int rank = 0;
        for (int k = 0; k < M; ++k) rank += (sc[k] > me) ? 1 : 0;
        if (rank < K) {
            uint32_t idx = ~(uint32_t)me;
            float v = ord2f((uint32_t)(me >> 32));
            float4 r = rects[idx];
            float* o = out + (size_t)rank * 5;
            o[0] = r.x; o[1] = r.y; o[2] = r.z; o[3] = r.w; o[4] = v;
        }
    }
}

extern "C" void kernel_launch(void* const* d_in, const int* in_sizes, int n_in,
                              void* d_out, int out_size, void* d_ws, size_t ws_size,
                              hipStream_t stream) {
    const float4* rects = (const float4*)d_in[0];
    const float* scores = (const float*)d_in[1];
    const float* off1 = (const float*)d_in[2];
    const float* off2 = (const float*)d_in[3];
    int N = in_sizes[0] / 4;
    int num1 = in_sizes[2] / 4;
    int num2 = in_sizes[3] / 4;
    int NT = num1 > num2 ? num1 : num2;
    int K = out_size / 5;
    float* out = (float*)d_out;

    GridCfg g;
    int px = 0, py = 0;
    for (int q = 0; q < NLEV; ++q) {
        double cell = 9.6 * pow(1.4, (double)(q - 5));
        int nx = (int)floor(1333.0 / cell) + 2;
        int ny = (int)floor(800.0 / cell) + 2;
        g.nx[q] = nx; g.ny[q] = ny;
        g.prefX[q] = px; g.prefY[q] = py;
        px += nx; py += ny;
    }
    g.totY = py;
    uint64_t TOT = (uint64_t)px * (uint64_t)py;   // ~4.15M cells

    uint32_t slots, mult, smask;
    if (TOT <= (1u << 22)) {
        slots = 1u << 22; mult = ODDMULT; smask = slots - 1;
    } else {
        slots = (uint32_t)TOT; mult = 1u; smask = 0xFFFFFFFFu;
    }

    char* p = (char*)d_ws;
    uint64_t* vals = (uint64_t*)p; p += (size_t)NT * slots * 8;
    uint32_t* hist = (uint32_t*)p; p += (size_t)NBINS * 4;
    uint32_t* scal = (uint32_t*)p; p += 256;
    uint64_t* cand = (uint64_t*)p; p += (size_t)CANDCAP * 8;
    uint64_t* P    = (uint64_t*)p; p += (size_t)N * 8;
    uint64_t* S    = (uint64_t*)p; p += (size_t)N * 8;
    uint64_t* KL   = (uint64_t*)p;

    size_t tblBytes = (size_t)NT * slots * 8;
    int blocks = (N + THREADS - 1) / THREADS;

    // one zero-init covers tables + hist + scal (contiguous)
    hipMemsetAsync(vals, 0, tblBytes + (size_t)NBINS * 4 + 256, stream);

    // stage 1: filtered returning atomicMax + provisional list P
    k_insert1<<<blocks, THREADS, 0, stream>>>(rects, scores, off1, num1, vals,
                                              P, scal, N, g, slots, mult, smask);
    // verify provisional winners -> survivors S (stage-2 packed)
    k_confirm<<<SGRID, THREADS, 0, stream>>>(rects, off1, num1, vals, P, S,
                                             scal, g, slots, mult, smask);
    // stage 2: survivors insert (epoch trick: MSB=1 beats stage-1 residue)
    k_insert2<<<SGRID, THREADS, 0, stream>>>(rects, off2, num2, vals, S, scal,
                                             g, slots, mult, smask);
    // rerank survivors -> histogram + keeplist
    k_resolve2<<<SGRID, THREADS, 0, stream>>>(rects, off2, num2, vals, S, KL,
                                              hist, scal, g, slots, mult, smask);

    // top-k
    k_thresh<<<1, 1024, 0, stream>>>(hist, scal, K);
    k_compact<<<SGRID, THREADS, 0, stream>>>(KL, cand, scal);
    k_topk<<<1, 1024, 0, stream>>>(rects, cand, scal, out, K);
}

// Round 9
// 270.898 us; speedup vs baseline: 1.4520x; 1.0303x over previous
//
#include <hip/hip_runtime.h>
#include <stdint.h>
#include <math.h>

#define THREADS 256
#define NBINS 65536
#define CANDCAP 8128
#define NLEV 15        // qw,qh in [-5, 9] -> t = q+5 in [0,14]
#define ODDMULT 0x9E3779B1u
#define SGRID 2048     // grid-stride blocks for list-driven passes

struct GridCfg {
    int prefX[NLEV], prefY[NLEV], nx[NLEV], ny[NLEV];
    int totY;
};

__device__ __forceinline__ uint32_t f2ord(float f) {
    uint32_t u = __float_as_uint(f);
    return (u & 0x80000000u) ? ~u : (u | 0x80000000u);
}
__device__ __forceinline__ float ord2f(uint32_t u) {
    uint32_t b = (u & 0x80000000u) ? (u ^ 0x80000000u) : ~u;
    return __uint_as_float(b);
}

// Perfect-hash slot: odd-mult scatter over [0, 2^22) (bijective while
// TOT <= 2^22). Numerics must bit-match the reference: f32 ops, no FMA
// contraction, correctly-rounded log/pow via double.
__device__ __forceinline__ uint32_t slot_of(float cx, float cy, float Lw, float Lh,
                                            float dw, float dh, float dx, float dy,
                                            const float* __restrict__ powtab,
                                            const GridCfg& g, uint32_t mult,
                                            uint32_t smask) {
#pragma clang fp contract(off)
    float qw = floorf(Lw + dw);
    float qh = floorf(Lh + dh);
    int iw = (int)qw, ih = (int)qh;
    int t = iw + 5; t = t < 0 ? 0 : (t > NLEV - 1 ? NLEV - 1 : t);
    int u = ih + 5; u = u < 0 ? 0 : (u > NLEV - 1 ? NLEV - 1 : u);
    float cellx = 9.6f * powtab[t];
    float celly = 9.6f * powtab[u];
    float qx = floorf(cx / cellx + dx);
    float qy = floorf(cy / celly + dy);
    int ix = (int)qx, iy = (int)qy;
    ix = ix < 0 ? 0 : (ix > g.nx[t] - 1 ? g.nx[t] - 1 : ix);
    iy = iy < 0 ? 0 : (iy > g.ny[u] - 1 ? g.ny[u] - 1 : iy);
    uint32_t cell = (uint32_t)((g.prefX[t] + ix) * g.totY + (g.prefY[u] + iy));
    return (cell * mult) & smask;
}

__device__ __forceinline__ void load_tabs(const float* __restrict__ offs, int num_off,
                                          float* powtab, float* soff) {
    int t = threadIdx.x;
    if (t < NLEV) powtab[t] = (float)pow((double)1.4f, (double)(t - 5));
    if (t >= 32 && t - 32 < num_off * 4) soff[t - 32] = offs[t - 32];
    __syncthreads();
}

__device__ __forceinline__ void compute_LwLh(float w, float h, float& Lw, float& Lh) {
#pragma clang fp contract(off)
    const float lg = (float)log((double)1.4f);
    Lw = (float)log((double)(w * 0.0625f)) / lg;
    Lh = (float)log((double)(h * 0.0625f)) / lg;
}

// ---- insert1: filtered NON-returning atomicMax; provisional-winner test on
// the filter reads alone (all cur[k] < packed). Superset guarantee: values
// are monotone and the true winner's packed is the strict max of its buckets,
// so every read (stale or fresh) shows < packed. Losers sneak in (verified by
// k_confirm). packed1 has MSB=0 (ord ^ 0x80000000, valid since s in [0,1)) so
// stage-2 values (MSB=1) beat all stage-1 residue (epoch trick).
__global__ void k_insert1(const float4* __restrict__ rects,
                          const float* __restrict__ scores,
                          const float* __restrict__ offs, int num_off,
                          uint64_t* __restrict__ vals,
                          uint64_t* __restrict__ Ppacked,
                          uint4* __restrict__ Pslots, int use_slots,
                          uint32_t* __restrict__ scal,
                          int N, GridCfg g, uint32_t slots, uint32_t mult,
                          uint32_t smask) {
#pragma clang fp contract(off)
    __shared__ float powtab[NLEV];
    __shared__ float soff[32];
    __shared__ uint32_t l_cnt, l_base;
    if (threadIdx.x == 0) l_cnt = 0;
    load_tabs(offs, num_off, powtab, soff);   // contains __syncthreads()

    int i = blockIdx.x * blockDim.x + threadIdx.x;
    bool win = false;
    uint64_t packed = 0;
    uint32_t sl[8];
    if (i < N) {
        float4 r = rects[i];
        float s = scores[i];
        packed = ((uint64_t)(f2ord(s) ^ 0x80000000u) << 32) | (uint32_t)(~(uint32_t)i);
        float Lw, Lh; compute_LwLh(r.z, r.w, Lw, Lh);
        for (int k = 0; k < num_off; ++k)
            sl[k] = slot_of(r.x, r.y, Lw, Lh,
                            soff[k * 4 + 0], soff[k * 4 + 1],
                            soff[k * 4 + 2], soff[k * 4 + 3], powtab, g, mult, smask);
        uint64_t cur[8];
        for (int k = 0; k < num_off; ++k)
            cur[k] = vals[(uint64_t)k * slots + sl[k]];
        win = true;
        for (int k = 0; k < num_off; ++k) {
            if (cur[k] < packed)
                atomicMax((unsigned long long*)&vals[(uint64_t)k * slots + sl[k]],
                          (unsigned long long)packed);
            else
                win = false;
        }
    }
    uint32_t pos = 0;
    if (win) pos = atomicAdd(&l_cnt, 1u);
    __syncthreads();
    if (threadIdx.x == 0 && l_cnt) l_base = atomicAdd(&scal[2], l_cnt);
    __syncthreads();
    if (win) {
        Ppacked[l_base + pos] = packed;
        if (use_slots)
            Pslots[l_base + pos] = make_uint4(sl[0], sl[1],
                                              num_off > 2 ? sl[2] : 0,
                                              num_off > 3 ? sl[3] : 0);
    }
}

// ---- confirm (resolve1 over P only): keep iff final winner of every bucket;
// survivors S hold stage-2 packed (MSB flipped on). Table read-only here, so
// cached values are final post-insert1 state.
__global__ void k_confirm(const float4* __restrict__ rects,
                          const float* __restrict__ offs, int num_off,
                          const uint64_t* __restrict__ vals,
                          const uint64_t* __restrict__ Ppacked,
                          const uint4* __restrict__ Pslots, int use_slots,
                          uint64_t* __restrict__ S,
                          uint32_t* __restrict__ scal,
                          GridCfg g, uint32_t slots, uint32_t mult,
                          uint32_t smask) {
#pragma clang fp contract(off)
    __shared__ float powtab[NLEV];
    __shared__ float soff[32];
    __shared__ uint32_t l_cnt, l_base;
    load_tabs(offs, num_off, powtab, soff);
    uint32_t total = scal[2];
    uint32_t stride = gridDim.x * blockDim.x;
    for (uint32_t base = blockIdx.x * blockDim.x; base < total; base += stride) {
        if (threadIdx.x == 0) l_cnt = 0;
        __syncthreads();
        uint32_t j = base + threadIdx.x;
        bool ok = false;
        uint64_t p1 = 0;
        if (j < total) {
            p1 = Ppacked[j];
            uint32_t sl[8];
            if (use_slots) {
                uint4 q = Pslots[j];
                sl[0] = q.x; sl[1] = q.y; sl[2] = q.z; sl[3] = q.w;
            } else {
                uint32_t i = ~(uint32_t)p1;
                float4 r = rects[i];
                float Lw, Lh; compute_LwLh(r.z, r.w, Lw, Lh);
                for (int k = 0; k < num_off; ++k)
                    sl[k] = slot_of(r.x, r.y, Lw, Lh,
                                    soff[k * 4 + 0], soff[k * 4 + 1],
                                    soff[k * 4 + 2], soff[k * 4 + 3],
                                    powtab, g, mult, smask);
            }
            ok = true;
            for (int k = 0; k < num_off; ++k)
                ok = ok && (vals[(uint64_t)k * slots + sl[k]] == p1);
        }
        uint32_t pos = 0;
        if (ok) pos = atomicAdd(&l_cnt, 1u);
        __syncthreads();
        if (threadIdx.x == 0 && l_cnt) l_base = atomicAdd(&scal[3], l_cnt);
        __syncthreads();
        if (ok) S[l_base + pos] = p1 ^ 0x8000000000000000ull;   // stage-2 packed
        __syncthreads();
    }
}

// ---- insert2: filtered non-returning atomicMax for survivors only.
// Stage-2 packed has MSB=1 -> beats any stale stage-1 entry (epoch trick).
__global__ void k_insert2(const float4* __restrict__ rects,
                          const float* __restrict__ offs, int num_off,
                          uint64_t* __restrict__ vals,
                          const uint64_t* __restrict__ S,
                          const uint32_t* __restrict__ scal,
                          GridCfg g, uint32_t slots, uint32_t mult,
                          uint32_t smask) {
#pragma clang fp contract(off)
    __shared__ float powtab[NLEV];
    __shared__ float soff[32];
    load_tabs(offs, num_off, powtab, soff);
    uint32_t total = scal[3];
    uint32_t stride = gridDim.x * blockDim.x;
    for (uint32_t j = blockIdx.x * blockDim.x + threadIdx.x; j < total; j += stride) {
        uint64_t p2 = S[j];
        uint32_t i = ~(uint32_t)p2;
        float4 r = rects[i];
        float Lw, Lh; compute_LwLh(r.z, r.w, Lw, Lh);
        uint32_t sl[8];
        for (int k = 0; k < num_off; ++k)
            sl[k] = slot_of(r.x, r.y, Lw, Lh,
                            soff[k * 4 + 0], soff[k * 4 + 1],
                            soff[k * 4 + 2], soff[k * 4 + 3], powtab, g, mult, smask);
        uint64_t cur[8];
        for (int k = 0; k < num_off; ++k)
            cur[k] = vals[(uint64_t)k * slots + sl[k]];
        for (int k = 0; k < num_off; ++k)
            if (cur[k] < p2)
                atomicMax((unsigned long long*)&vals[(uint64_t)k * slots + sl[k]],
                          (unsigned long long)p2);
    }
}

// ---- resolve2: survivors only. rep = final stage-2 bucket winner (my bucket
// always holds an MSB=1 value >= mine). keep iff rep==me or IoU<=0.5 in all
// tables; keepers -> histogram + keeplist (block-aggregated).
__global__ void k_resolve2(const float4* __restrict__ rects,
                           const float* __restrict__ offs, int num_off,
                           const uint64_t* __restrict__ vals,
                           const uint64_t* __restrict__ S,
                           uint64_t* __restrict__ KL,
                           uint32_t* __restrict__ hist,
                           uint32_t* __restrict__ scal,
                           GridCfg g, uint32_t slots, uint32_t mult,
                           uint32_t smask) {
#pragma clang fp contract(off)
    __shared__ float powtab[NLEV];
    __shared__ float soff[32];
    __shared__ uint32_t l_cnt, l_base;
    load_tabs(offs, num_off, powtab, soff);
    uint32_t total = scal[3];
    uint32_t stride = gridDim.x * blockDim.x;
    for (uint32_t base = blockIdx.x * blockDim.x; base < total; base += stride) {
        if (threadIdx.x == 0) l_cnt = 0;
        __syncthreads();
        uint32_t j = base + threadIdx.x;
        bool keep = false;
        uint64_t p2 = 0;
        float s = 0.0f;
        if (j < total) {
            p2 = S[j];
            uint32_t i = ~(uint32_t)p2;
            s = ord2f((uint32_t)(p2 >> 32));
            float4 a = rects[i];
            float Lw, Lh; compute_LwLh(a.z, a.w, Lw, Lh);
            keep = true;
            for (int k = 0; k < num_off && keep; ++k) {
                uint32_t sl = slot_of(a.x, a.y, Lw, Lh,
                                      soff[k * 4 + 0], soff[k * 4 + 1],
                                      soff[k * 4 + 2], soff[k * 4 + 3],
                                      powtab, g, mult, smask);
                uint64_t v = vals[(uint64_t)k * slots + sl];
                uint32_t rep = ~(uint32_t)v;
                if (rep != i) {
                    float4 b = rects[rep];
                    float ax1 = a.x - 0.5f * a.z, ay1 = a.y - 0.5f * a.w;
                    float ax2 = a.x + 0.5f * a.z, ay2 = a.y + 0.5f * a.w;
                    float bx1 = b.x - 0.5f * b.z, by1 = b.y - 0.5f * b.w;
                    float bx2 = b.x + 0.5f * b.z, by2 = b.y + 0.5f * b.w;
                    float iw = fminf(ax2, bx2) - fmaxf(ax1, bx1); iw = fmaxf(iw, 0.0f);
                    float ih = fminf(ay2, by2) - fmaxf(ay1, by1); ih = fmaxf(ih, 0.0f);
                    float inter = iw * ih;
                    float uni = a.z * a.w + b.z * b.w - inter;
                    float iou = inter / fmaxf(uni, 1e-12f);
                    keep = keep && (iou <= 0.5f);
                }
            }
        }
        if (keep) {
            int b = (int)(s * 65536.0f);
            b = b < 0 ? 0 : (b > NBINS - 1 ? NBINS - 1 : b);
            atomicAdd(&hist[b], 1u);
        }
        uint32_t pos = 0;
        if (keep) pos = atomicAdd(&l_cnt, 1u);
        __syncthreads();
        if (threadIdx.x == 0 && l_cnt) l_base = atomicAdd(&scal[4], l_cnt);
        __syncthreads();
        if (keep) KL[l_base + pos] = p2;
        __syncthreads();
    }
}

// ---- threshold bin: largest T with count(bin >= T) >= K ----
__global__ void k_thresh(const uint32_t* __restrict__ hist,
                         uint32_t* __restrict__ scal, int K) {
    __shared__ uint32_t sh[1024];
    __shared__ int tmax;
    __shared__ uint32_t running_s;
    int t = threadIdx.x;
    if (t == 0) { running_s = 0; scal[0] = 0; }
    __syncthreads();
    for (int base = NBINS - 1024; base >= 0; base -= 1024) {
        if (t == 0) tmax = -1;
        sh[t] = hist[base + t];
        __syncthreads();
        for (int off = 1; off < 1024; off <<= 1) {
            uint32_t v = (t + off < 1024) ? sh[t + off] : 0u;
            __syncthreads();
            sh[t] += v;
            __syncthreads();
        }
        if (running_s + sh[t] >= (uint32_t)K) atomicMax(&tmax, t);
        __syncthreads();
        if (tmax >= 0) {
            if (t == 0) scal[0] = (uint32_t)(base + tmax);
            return;
        }
        if (t == 0) running_s += sh[0];
        __syncthreads();
    }
}

// ---- compact keepers above threshold bin into cand ----
__global__ void k_compact(const uint64_t* __restrict__ KL,
                          uint64_t* __restrict__ cand,
                          uint32_t* __restrict__ scal) {
    uint32_t total = scal[4];
    uint32_t thr = scal[0];
    uint32_t stride = gridDim.x * blockDim.x;
    for (uint32_t j = blockIdx.x * blockDim.x + threadIdx.x; j < total; j += stride) {
        uint64_t p = KL[j];
        float v = ord2f((uint32_t)(p >> 32));
        int b = (int)(v * 65536.0f);
        b = b < 0 ? 0 : (b > NBINS - 1 ? NBINS - 1 : b);
        if (b >= (int)thr) {
            uint32_t pos = atomicAdd(&scal[1], 1u);
            if (pos < CANDCAP) cand[pos] = p;
        }
    }
}

// ---- exact rank (value desc, idx asc), emit [rects[idx], val] rows ----
__global__ void k_topk(const float4* __restrict__ rects,
                       const uint64_t* __restrict__ cand,
                       const uint32_t* __restrict__ scal,
                       float* __restrict__ out, int K) {
    __shared__ uint64_t sc[CANDCAP];
    int t = threadIdx.x;
    int M = (int)scal[1]; if (M > CANDCAP) M = CANDCAP;
    for (int j = t; j < M; j += blockDim.x) sc[j] = cand[j];
    __syncthreads();
    for (int j = t; j < M; j += blockDim.x) {
        uint64_t me = sc[j];
        int rank = 0;
        for (int k = 0; k < M; ++k) rank += (sc[k] > me) ? 1 : 0;
        if (rank < K) {
            uint32_t idx = ~(uint32_t)me;
            float v = ord2f((uint32_t)(me >> 32));
            float4 r = rects[idx];
            float* o = out + (size_t)rank * 5;
            o[0] = r.x; o[1] = r.y; o[2] = r.z; o[3] = r.w; o[4] = v;
        }
    }
}

extern "C" void kernel_launch(void* const* d_in, const int* in_sizes, int n_in,
                              void* d_out, int out_size, void* d_ws, size_t ws_size,
                              hipStream_t stream) {
    const float4* rects = (const float4*)d_in[0];
    const float* scores = (const float*)d_in[1];
    const float* off1 = (const float*)d_in[2];
    const float* off2 = (const float*)d_in[3];
    int N = in_sizes[0] / 4;
    int num1 = in_sizes[2] / 4;
    int num2 = in_sizes[3] / 4;
    int NT = num1 > num2 ? num1 : num2;
    int K = out_size / 5;
    float* out = (float*)d_out;

    GridCfg g;
    int px = 0, py = 0;
    for (int q = 0; q < NLEV; ++q) {
        double cell = 9.6 * pow(1.4, (double)(q - 5));
        int nx = (int)floor(1333.0 / cell) + 2;
        int ny = (int)floor(800.0 / cell) + 2;
        g.nx[q] = nx; g.ny[q] = ny;
        g.prefX[q] = px; g.prefY[q] = py;
        px += nx; py += ny;
    }
    g.totY = py;
    uint64_t TOT = (uint64_t)px * (uint64_t)py;   // ~4.15M cells

    uint32_t slots, mult, smask;
    if (TOT <= (1u << 22)) {
        slots = 1u << 22; mult = ODDMULT; smask = slots - 1;
    } else {
        slots = (uint32_t)TOT; mult = 1u; smask = 0xFFFFFFFFu;
    }

    // workspace layout (KL aliases Ppacked — P dead after k_confirm):
    char* p = (char*)d_ws;
    uint64_t* vals    = (uint64_t*)p; p += (size_t)NT * slots * 8;
    uint32_t* hist    = (uint32_t*)p; p += (size_t)NBINS * 4;
    uint32_t* scal    = (uint32_t*)p; p += 256;
    uint64_t* cand    = (uint64_t*)p; p += (size_t)CANDCAP * 8;
    uint64_t* Ppacked = (uint64_t*)p; p += (size_t)N * 8;
    uint64_t* S       = (uint64_t*)p; p += (size_t)N * 8;
    uint64_t* KL      = Ppacked;
    uint4*    Pslots  = (uint4*)p;    // + N*16 if it fits
    size_t base_need = (size_t)(p - (char*)d_ws);
    int use_slots = (num1 <= 4 && base_need + (size_t)N * 16 <= ws_size) ? 1 : 0;

    size_t tblBytes = (size_t)NT * slots * 8;
    int blocks = (N + THREADS - 1) / THREADS;

    // one zero-init covers tables + hist + scal (contiguous)
    hipMemsetAsync(vals, 0, tblBytes + (size_t)NBINS * 4 + 256, stream);

    // stage 1: filtered non-returning atomicMax + provisional list P
    k_insert1<<<blocks, THREADS, 0, stream>>>(rects, scores, off1, num1, vals,
                                              Ppacked, Pslots, use_slots, scal,
                                              N, g, slots, mult, smask);
    // verify provisional winners -> survivors S (stage-2 packed)
    k_confirm<<<SGRID, THREADS, 0, stream>>>(rects, off1, num1, vals, Ppacked,
                                             Pslots, use_slots, S, scal, g,
                                             slots, mult, smask);
    // stage 2: survivors insert (epoch trick: MSB=1 beats stage-1 residue)
    k_insert2<<<SGRID, THREADS, 0, stream>>>(rects, off2, num2, vals, S, scal,
                                             g, slots, mult, smask);
    // rerank survivors -> histogram + keeplist
    k_resolve2<<<SGRID, THREADS, 0, stream>>>(rects, off2, num2, vals, S, KL,
                                              hist, scal, g, slots, mult, smask);

    // top-k
    k_thresh<<<1, 1024, 0, stream>>>(hist, scal, K);
    k_compact<<<SGRID, THREADS, 0, stream>>>(KL, cand, scal);
    k_topk<<<1, 1024, 0, stream>>>(rects, cand, scal, out, K);
}